// Round 1
// baseline (120.119 us; speedup 1.0000x reference)
//
#include <hip/hip_runtime.h>

// SPU bound transformer: element-wise over (N,2) fp32 rows.
// Pure stream: 67 MB in + 67 MB out, zero reuse (harness poison fills thrash L3
// between replays). Target = HBM stream BW (~6.45 TB/s demonstrated by fills).
//
// v2 changes vs 108 µs baseline:
//  - 4 float4s per thread (4 independent loads in flight -> MLP, fewer waves)
//  - division-free: sign(slope) == sign(vu - vl) since u - l > 0 in the cross
//    case; sigmoid uses v_rcp_f32 (tolerance 7.8e-3 >> rcp's ~1e-7 error)
//  - non-temporal load/store hints (no reuse inside timed window)

typedef float f32x4 __attribute__((ext_vector_type(4)));

__device__ __forceinline__ float spu_f(float x) {
    // x >= 0: x*x - 0.5
    // x <  0: sigmoid(-x) - 1 = -e^x / (1 + e^x)
    float t = __expf(x);                               // v_exp_f32 (+1 mul)
    float negbr = -t * __builtin_amdgcn_rcpf(1.0f + t); // v_rcp_f32, no IEEE div
    float posbr = __fmaf_rn(x, x, -0.5f);
    return (x >= 0.0f) ? posbr : negbr;
}

__device__ __forceinline__ f32x4 spu_pair(f32x4 v) {
    f32x4 r;
    // row 0: (v.x, v.y)  row 1: (v.z, v.w)
    #pragma unroll
    for (int k = 0; k < 2; ++k) {
        float l = (k == 0) ? v.x : v.z;
        float u = (k == 0) ? v.y : v.w;
        float vl = spu_f(l);
        float vu = spu_f(u);
        bool neg   = (u <= 0.0f);
        bool pos   = (l >= 0.0f);
        bool cross = !(neg || pos);
        // cross => l < 0 < u => u - l > 0 strictly, so slope >= 0 <=> vu >= vl.
        bool cpos  = cross && (vu >= vl);
        bool cneg  = cross && (vu <  vl);
        float lo = neg ? vl : (cpos ? -0.5f : 0.0f);
        float up = neg ? vu : (cpos ? vu : (cneg ? vl : 0.0f));
        if (k == 0) { r.x = lo; r.y = up; }
        else        { r.z = lo; r.w = up; }
    }
    return r;
}

__global__ __launch_bounds__(256) void spu_kernel(const f32x4* __restrict__ in,
                                                  f32x4* __restrict__ out,
                                                  int n4) {
    const int T = gridDim.x * blockDim.x;
    int i = blockIdx.x * blockDim.x + threadIdx.x;

    // Main loop: 4 independent NT loads in flight, then compute, then 4 NT stores.
    for (; i + 3 * T < n4; i += 4 * T) {
        f32x4 a = __builtin_nontemporal_load(in + i);
        f32x4 b = __builtin_nontemporal_load(in + i + T);
        f32x4 c = __builtin_nontemporal_load(in + i + 2 * T);
        f32x4 d = __builtin_nontemporal_load(in + i + 3 * T);
        f32x4 ra = spu_pair(a);
        f32x4 rb = spu_pair(b);
        f32x4 rc = spu_pair(c);
        f32x4 rd = spu_pair(d);
        __builtin_nontemporal_store(ra, out + i);
        __builtin_nontemporal_store(rb, out + i + T);
        __builtin_nontemporal_store(rc, out + i + 2 * T);
        __builtin_nontemporal_store(rd, out + i + 3 * T);
    }
    // Tail (never taken for n4 = 4194304 with 4096 blocks, kept for generality).
    for (; i < n4; i += T) {
        f32x4 a = __builtin_nontemporal_load(in + i);
        f32x4 ra = spu_pair(a);
        __builtin_nontemporal_store(ra, out + i);
    }
}

extern "C" void kernel_launch(void* const* d_in, const int* in_sizes, int n_in,
                              void* d_out, int out_size, void* d_ws, size_t ws_size,
                              hipStream_t stream) {
    const f32x4* in = (const f32x4*)d_in[0];
    f32x4* out = (f32x4*)d_out;
    int n4 = out_size / 4;                 // 8388608*2 floats / 4 = 4194304
    const int threads = 256;
    const int per_thread = 4;
    int blocks = (n4 + threads * per_thread - 1) / (threads * per_thread);  // 4096
    spu_kernel<<<blocks, threads, 0, stream>>>(in, out, n4);
}

// Round 2
// 108.688 us; speedup vs baseline: 1.1052x; 1.1052x over previous
//
#include <hip/hip_runtime.h>

// SPU bound transformer: element-wise over (N,2) fp32 rows.
// Pure stream: 67 MB in + 67 MB out. Memory-bound.
//
// v3 = baseline memory structure (1 float4/thread, plain loads/stores — the
// measured-good ~24 µs pattern) + compute-only simplifications:
//  - slope division deleted: in the cross case u - l > 0 strictly, so
//    sign(slope) == sign(vu - vl)
//  - sigmoid via v_rcp_f32 instead of IEEE div (err ~1e-7, tol 7.8e-3)
// Round-1 lesson: NT hints / 4-way 16MB-strided streams cost +50% kernel time.

__device__ __forceinline__ float spu_f(float x) {
    // x >= 0: x*x - 0.5
    // x <  0: sigmoid(-x) - 1 = -e^x / (1 + e^x)
    float t = __expf(x);                                // v_exp_f32 (+mul)
    float negbr = -t * __builtin_amdgcn_rcpf(1.0f + t); // v_rcp_f32
    float posbr = __fmaf_rn(x, x, -0.5f);
    return (x >= 0.0f) ? posbr : negbr;
}

__device__ __forceinline__ void spu_row(float l, float u, float& lower, float& upper) {
    float vl = spu_f(l);
    float vu = spu_f(u);
    bool neg   = (u <= 0.0f);
    bool pos   = (l >= 0.0f);
    bool cross = !(neg || pos);
    // cross => l < 0 < u => u - l > 0, so slope >= 0  <=>  vu >= vl.
    bool cpos  = cross && (vu >= vl);
    bool cneg  = cross && (vu <  vl);
    lower = neg ? vl : (cpos ? -0.5f : 0.0f);
    upper = neg ? vu : (cpos ? vu : (cneg ? vl : 0.0f));
}

__global__ __launch_bounds__(256) void spu_kernel(const float4* __restrict__ in,
                                                  float4* __restrict__ out,
                                                  int n4) {
    int i = blockIdx.x * blockDim.x + threadIdx.x;
    if (i >= n4) return;
    float4 v = in[i];           // two rows: (l0,u0,l1,u1)
    float4 r;
    spu_row(v.x, v.y, r.x, r.y);
    spu_row(v.z, v.w, r.z, r.w);
    out[i] = r;
}

extern "C" void kernel_launch(void* const* d_in, const int* in_sizes, int n_in,
                              void* d_out, int out_size, void* d_ws, size_t ws_size,
                              hipStream_t stream) {
    const float4* in = (const float4*)d_in[0];
    float4* out = (float4*)d_out;
    int n4 = out_size / 4;                 // 8388608*2 floats / 4 = 4194304
    int threads = 256;
    int blocks = (n4 + threads - 1) / threads;   // 16384
    spu_kernel<<<blocks, threads, 0, stream>>>(in, out, n4);
}